// Round 9
// baseline (203.935 us; speedup 1.0000x reference)
//
#include <hip/hip_runtime.h>

// Deinterleave x[B,C,H,W] (fp32, H=W=256) into 4 quadrant tensors:
//   ll = x[:,:,0::2,0::2], lh = x[:,:,0::2,1::2],
//   hl = x[:,:,1::2,0::2], hh = x[:,:,1::2,1::2]
// d_out = [ll | lh | hl | hh] flat, each of size B*C*128*128 floats.
//
// R9: write-burst locality test. One wave-iteration = 8 consecutive input
// rows (8 KB), eight dense 1KB wave-contiguous PLAIN loads (R8 showed NT
// loads cost ~4%), then stores GROUPED BY QUADRANT: the 8 rows produce 4
// consecutive output rows per quadrant = one contiguous 2KB region, issued
// as 4 back-to-back ascending 512B NT store segments per stream (vs R4's
// isolated 512B bursts round-robined across streams).

typedef float f32x4 __attribute__((ext_vector_type(4)));
typedef float f32x2 __attribute__((ext_vector_type(2)));

__global__ __launch_bounds__(256) void deinterleave2x2_kernel(
    const f32x4* __restrict__ in,    // input viewed as 16B vectors
    float* __restrict__ out,         // base of concatenated outputs
    size_t nitems,                   // total work items = N/32
    size_t outsz)                    // elements per output tensor
{
    const size_t stride = (size_t)gridDim.x * blockDim.x;
    for (size_t t = (size_t)blockIdx.x * blockDim.x + threadIdx.x;
         t < nitems; t += stride) {
        const size_t l   = t & 63;          // lane within wave
        const size_t G   = t >> 6;          // group = 8 consecutive rows
        const size_t img = G >> 5;          // 32 groups per (b,c) image
        const size_t gi  = G & 31;          // group within image

        const size_t ib = 512 * G + l;      // input f4 base for this lane

        // 8 dense 1KB wave-contiguous loads (plain; L2 write-back path).
        f32x4 v[8];
#pragma unroll
        for (int k = 0; k < 8; ++k)
            v[k] = in[ib + 64 * (size_t)k];

        // Output image 128x128; group covers out rows 4*gi .. 4*gi+3 in
        // every quadrant: floats [gi*512, gi*512+512) — contiguous 2KB.
        const size_t off = img * (size_t)(128 * 128) + gi * 512 + 2 * l;

        f32x2 w;
        // stream 0: ll  (even rows k=0,2,4,6; even cols)
#pragma unroll
        for (int r = 0; r < 4; ++r) {
            w.x = v[2 * r].x; w.y = v[2 * r].z;
            __builtin_nontemporal_store(w,
                reinterpret_cast<f32x2*>(out + off + (size_t)r * 128));
        }
        // stream 1: lh  (even rows; odd cols)
#pragma unroll
        for (int r = 0; r < 4; ++r) {
            w.x = v[2 * r].y; w.y = v[2 * r].w;
            __builtin_nontemporal_store(w,
                reinterpret_cast<f32x2*>(out + outsz + off + (size_t)r * 128));
        }
        // stream 2: hl  (odd rows k=1,3,5,7; even cols)
#pragma unroll
        for (int r = 0; r < 4; ++r) {
            w.x = v[2 * r + 1].x; w.y = v[2 * r + 1].z;
            __builtin_nontemporal_store(w,
                reinterpret_cast<f32x2*>(out + 2 * outsz + off + (size_t)r * 128));
        }
        // stream 3: hh  (odd rows; odd cols)
#pragma unroll
        for (int r = 0; r < 4; ++r) {
            w.x = v[2 * r + 1].y; w.y = v[2 * r + 1].w;
            __builtin_nontemporal_store(w,
                reinterpret_cast<f32x2*>(out + 3 * outsz + off + (size_t)r * 128));
        }
    }
}

extern "C" void kernel_launch(void* const* d_in, const int* in_sizes, int n_in,
                              void* d_out, int out_size, void* d_ws, size_t ws_size,
                              hipStream_t stream) {
    const float* x = (const float*)d_in[0];
    float* out = (float*)d_out;

    const size_t total  = (size_t)in_sizes[0];      // B*C*H*W = 8*256*256*256
    const size_t nitems = total >> 5;               // 32 floats per work item
    const size_t outsz  = total >> 2;               // each output = total/4

    const int threads = 256;
    const int blocks  = 2048;                        // 8 blocks/CU on 256 CUs

    deinterleave2x2_kernel<<<blocks, threads, 0, stream>>>(
        reinterpret_cast<const f32x4*>(x), out, nitems, outsz);
}

// Round 10
// 191.637 us; speedup vs baseline: 1.0642x; 1.0642x over previous
//
#include <hip/hip_runtime.h>

// Deinterleave x[B,C,H,W] (fp32, H=W=256) into 4 quadrant tensors:
//   ll = x[:,:,0::2,0::2], lh = x[:,:,0::2,1::2],
//   hl = x[:,:,1::2,0::2], hh = x[:,:,1::2,1::2]
// d_out = [ll | lh | hl | hh] flat, each of size B*C*128*128 floats.
//
// FINAL (= R4, best of 9 variants @ 191.6us = 5.60 TB/s effective, 89% of
// the 6.29 TB/s copy ceiling). Empirically settled choices:
//   - loads: dense 1KB wave-contiguous float4, PLAIN (NT loads cost ~4%)
//   - stores: 8B NT f32x2, round-robin across the 4 quadrant streams
//     (NT stores worth +4.5%; 16B-wide or burst-grouped variants regress)
//   - batch: 4 input rows / wave-iteration (8 rows regresses ~4%)
// Remaining gap to copy BW is the 1R+4W multi-stream DRAM mix cost.
//
// One wave-iteration = one GROUP of 2 row-pairs (4 input rows = 4 KB).
// Lane l loads 4 wave-contiguous 1KB segments (rows 4g..4g+3) and emits
// 8x 8B stores, each a 512B-dense wave segment into one quadrant.

typedef float f32x4 __attribute__((ext_vector_type(4)));
typedef float f32x2 __attribute__((ext_vector_type(2)));

__global__ __launch_bounds__(256) void deinterleave2x2_kernel(
    const f32x4* __restrict__ in,    // input viewed as 16B vectors
    float* __restrict__ out,         // base of concatenated outputs
    size_t nitems,                   // total work items = N/16
    size_t outsz)                    // elements per output tensor
{
    const size_t stride = (size_t)gridDim.x * blockDim.x;
    for (size_t t = (size_t)blockIdx.x * blockDim.x + threadIdx.x;
         t < nitems; t += stride) {
        const size_t l   = t & 63;          // lane-within-group
        const size_t g   = t >> 6;          // group = 2 row-pairs = 4 rows
        const size_t rp  = (g & 63) * 2;    // first row-pair within image
        const size_t img = g >> 6;          // which (b,c) image

        const size_t ib = 256 * g + l;      // input f4 base for this lane
        const f32x4 e0 = in[ib];            // row 4g
        const f32x4 o0 = in[ib + 64];       // row 4g+1
        const f32x4 e1 = in[ib + 128];      // row 4g+2
        const f32x4 o1 = in[ib + 192];      // row 4g+3

        // Output image is 128x128; lane l owns output cols 2l, 2l+1.
        const size_t off0 = img * (size_t)(128 * 128) + rp * 128 + 2 * l;
        const size_t off1 = off0 + 128;

        f32x2 v;
        // row-pair 0
        v.x = e0.x; v.y = e0.z;
        __builtin_nontemporal_store(v, reinterpret_cast<f32x2*>(out + off0));
        v.x = e0.y; v.y = e0.w;
        __builtin_nontemporal_store(v, reinterpret_cast<f32x2*>(out + outsz + off0));
        v.x = o0.x; v.y = o0.z;
        __builtin_nontemporal_store(v, reinterpret_cast<f32x2*>(out + 2 * outsz + off0));
        v.x = o0.y; v.y = o0.w;
        __builtin_nontemporal_store(v, reinterpret_cast<f32x2*>(out + 3 * outsz + off0));
        // row-pair 1
        v.x = e1.x; v.y = e1.z;
        __builtin_nontemporal_store(v, reinterpret_cast<f32x2*>(out + off1));
        v.x = e1.y; v.y = e1.w;
        __builtin_nontemporal_store(v, reinterpret_cast<f32x2*>(out + outsz + off1));
        v.x = o1.x; v.y = o1.z;
        __builtin_nontemporal_store(v, reinterpret_cast<f32x2*>(out + 2 * outsz + off1));
        v.x = o1.y; v.y = o1.w;
        __builtin_nontemporal_store(v, reinterpret_cast<f32x2*>(out + 3 * outsz + off1));
    }
}

extern "C" void kernel_launch(void* const* d_in, const int* in_sizes, int n_in,
                              void* d_out, int out_size, void* d_ws, size_t ws_size,
                              hipStream_t stream) {
    const float* x = (const float*)d_in[0];
    float* out = (float*)d_out;

    const size_t total  = (size_t)in_sizes[0];      // B*C*H*W = 8*256*256*256
    const size_t nitems = total >> 4;               // 16 floats per work item
    const size_t outsz  = total >> 2;               // each output = total/4

    const int threads = 256;
    const int blocks  = 2048;                        // 8 waves/SIMD across 256 CUs

    deinterleave2x2_kernel<<<blocks, threads, 0, stream>>>(
        reinterpret_cast<const f32x4*>(x), out, nitems, outsz);
}